// Round 15
// baseline (605.121 us; speedup 1.0000x reference)
//
#include <hip/hip_runtime.h>
#include <stdint.h>

typedef int v4i  __attribute__((ext_vector_type(4)));
typedef int v16i __attribute__((ext_vector_type(16)));

#define CAPACITY  65536
#define BATCH     2048
#define KBITS     1024
#define NSTEP     16      // K-steps of 64 bytes

// ===========================================================================
// MFMA path: dist(q,k) = sumq + sumk - 2*dot(q,k). sumq constant per query
// row -> dropped; rank by packed ((sumk - 2*dot + 2048)<<16) | key_idx, exact
// (0 <= biased dist <= 3072 < 2^16), reproduces first-max argmax.
//
// Geometry: block 256(M) x 64(N), 4 waves = 4 M-rows (wave tile 64x64).
// r15 deltas vs r14 (which was phase-locked at MfmaUtil 25%):
//  (1) phase stagger: co-resident blocks sleep 0/768/1536/2304 cyc before the
//      prologue -> the 4 blocks/CU run ~1/4-step offset phases, so one
//      block's MFMA burst overlaps another's LDS/vmem burst instead of
//      serializing chip-wide.
//  (2) mtile-OUTER order: co-resident blocks share the A panel -> af loads
//      L1-hit (af was the largest per-step pipe demand).
// ===========================================================================

// ---- queries: bits -> i8, blocked-transposed qT[k/16][m][16] ----------------
__global__ void prep_qT_kernel(const int* __restrict__ in,
                               uint32_t* __restrict__ outT) {
    const int row = blockIdx.x, t = threadIdx.x;   // t covers bits 4t..4t+3
    int4 v = reinterpret_cast<const int4*>(in)[(size_t)row * 256 + t];
    uint32_t b = (uint32_t)(v.x & 1)        | ((uint32_t)(v.y & 1) << 8) |
                 ((uint32_t)(v.z & 1) << 16) | ((uint32_t)(v.w & 1) << 24);
    outT[(size_t)(t >> 2) * (BATCH * 4) + (size_t)row * 4 + (t & 3)] = b;
}

// ---- keys: bits -> i8 row-major, plus per-row bit count ---------------------
__global__ void prep_i8_kernel(const int* __restrict__ in,
                               unsigned char* __restrict__ out8,
                               int* __restrict__ sums) {
    const int row = blockIdx.x, t = threadIdx.x;
    int4 v = reinterpret_cast<const int4*>(in)[(size_t)row * 256 + t];
    uint32_t b = (uint32_t)(v.x & 1)        | ((uint32_t)(v.y & 1) << 8) |
                 ((uint32_t)(v.z & 1) << 16) | ((uint32_t)(v.w & 1) << 24);
    reinterpret_cast<uint32_t*>(out8)[(size_t)row * 256 + t] = b;
    int s = (v.x & 1) + (v.y & 1) + (v.z & 1) + (v.w & 1);
    for (int off = 32; off; off >>= 1) s += __shfl_xor(s, off, 64);
    __shared__ int ws4[4];
    if ((t & 63) == 0) ws4[t >> 6] = s;
    __syncthreads();
    if (t == 0) sums[row] = ws4[0] + ws4[1] + ws4[2] + ws4[3];
}

__global__ void init_best_kernel(uint32_t* __restrict__ best) {
    best[blockIdx.x * 256 + threadIdx.x] = 0xFFFFFFFFu;
}

// Involutive 16B-chunk swizzle within a [rows][64B] tile (idx = row*4+chunk):
// self-inverse, spreads consecutive rows across bank groups.
__device__ __forceinline__ int swz(int idx) { return idx ^ ((idx >> 3) & 7); }

// ---- GEMM + fused argmin ---------------------------------------------------
__launch_bounds__(256, 4)
__global__ void gemm_scan_kernel(const uint4* __restrict__ aT4,
                                 const unsigned char* __restrict__ ki8,
                                 const int* __restrict__ sumk,
                                 uint32_t* __restrict__ best) {
    __shared__ uint4 sB[3][256];   // 3 x (64 rows x 4 chunks) = 12 KB

    // ---- (1) phase stagger: desync co-resident blocks -------------------
    // Round-robin dispatch puts bid, bid+256, bid+512, bid+768 on one CU;
    // (bid>>8)&3 gives each a distinct ~1/4-step sleep (s_sleep n = ~64n cyc).
    {
        const int ph = (blockIdx.x >> 8) & 3;
        if (ph & 1) __builtin_amdgcn_s_sleep(12);   // +768 cyc
        if (ph & 2) __builtin_amdgcn_s_sleep(24);   // +1536 cyc
    }

    const int t    = threadIdx.x;
    const int lane = t & 63, wid = t >> 6;        // wid = wave M-row
    const int ln   = lane & 31, kh = lane >> 5;   // mfma lane, k-half

    // ---- (2) mtile-OUTER, XCD-pinned: xcd = b&7 owns 128 ntiles; ---------
    // co-resident blocks (slot +-32) share mtile 75% of the time -> shared
    // A panel (L1 hits). B tile unique per block, XCD L2/L3-resident.
    const int b     = blockIdx.x;
    const int slot  = b >> 3;                       // [0,1024)
    const int mtile = slot >> 7;                    // [0,8)   outer
    const int ntile = (b & 7) * 128 + (slot & 127); // [0,1024)
    const int m0 = mtile * 256, n0 = ntile * 64;

    // B staging source, pre-swizzled (swz involution; LDS dest linear):
    const int sidx = swz(t);
    const unsigned char* bSrc =
        ki8 + (size_t)(n0 + (sidx >> 2)) * KBITS + (sidx & 3) * 16;
    auto STAGE_B = [&](int buf, int kc) {          // 1 x global_load_lds(16B)
        __builtin_amdgcn_global_load_lds(
            (const __attribute__((address_space(1))) void*)(bSrc + kc),
            (__attribute__((address_space(3))) void*)&sB[buf][wid * 64],
            16, 0, 0);
    };

    // B fragment LDS offsets (K-invariant), shared tile for all waves
    int offB[2][2];
#pragma unroll
    for (int km = 0; km < 2; ++km)
#pragma unroll
        for (int ct = 0; ct < 2; ++ct)
            offB[km][ct] = swz((ct * 32 + ln) * 4 + km * 2 + kh);

    const int mbase = m0 + wid * 64 + ln;          // unique per wave

    v16i acc[2][2];
#pragma unroll
    for (int rt = 0; rt < 2; ++rt)
#pragma unroll
        for (int ct = 0; ct < 2; ++ct)
#pragma unroll
            for (int e = 0; e < 16; ++e) acc[rt][ct][e] = 0;

    uint4 afbuf[2][2][2];                          // [parity][km][rt]
    auto LOAD_AF = [&](int par, int s) {
#pragma unroll
        for (int km = 0; km < 2; ++km)
#pragma unroll
            for (int rt = 0; rt < 2; ++rt)
                afbuf[par][km][rt] = aT4[(size_t)(s * 4 + km * 2 + kh) * BATCH
                                         + mbase + rt * 32];
    };

    // prologue: queue = stage(0)[1], stage(1)[1], af(0)[4].
    // vmcnt(5) retires stage(0); stage(1)+af(0) stay in flight.
    STAGE_B(0, 0);
    STAGE_B(1, 64);
    LOAD_AF(0, 0);
    asm volatile("s_waitcnt vmcnt(5)" ::: "memory");
    __builtin_amdgcn_s_barrier();

#pragma unroll
    for (int s = 0; s < NSTEP; ++s) {
        const int par = s & 1, buf = s % 3;

        if (s + 1 < NSTEP) LOAD_AF(par ^ 1, s + 1);       // 4 vm, 1-step slack
        if (s + 2 < NSTEP) STAGE_B((s + 2) % 3, (s + 2) * 64); // 1 vm, 2-step

        // B fragments: km=0 pair then km=1 pair (counted lgkm overlap)
        uint4 bf0[2], bf1[2];
#pragma unroll
        for (int ct = 0; ct < 2; ++ct) bf0[ct] = sB[buf][offB[0][ct]];
#pragma unroll
        for (int ct = 0; ct < 2; ++ct) bf1[ct] = sB[buf][offB[1][ct]];

        // retire af(s) (+ all older, incl. stage(s)); bf0 ready.
        // younger left in flight: stage(s+1), af(s+1), stage(s+2).
        if (s == 0)
            asm volatile("s_waitcnt vmcnt(5) lgkmcnt(2)" ::: "memory");
        else if (s <= 13)
            asm volatile("s_waitcnt vmcnt(6) lgkmcnt(2)" ::: "memory");
        else if (s == 14)
            asm volatile("s_waitcnt vmcnt(5) lgkmcnt(2)" ::: "memory");
        else
            asm volatile("s_waitcnt vmcnt(0) lgkmcnt(2)" ::: "memory");
        __builtin_amdgcn_sched_barrier(0);

        __builtin_amdgcn_s_setprio(1);
#pragma unroll
        for (int rt = 0; rt < 2; ++rt)
#pragma unroll
            for (int ct = 0; ct < 2; ++ct)
                acc[rt][ct] = __builtin_amdgcn_mfma_i32_32x32x32_i8(
                    *(v4i*)&afbuf[par][0][rt], *(v4i*)&bf0[ct], acc[rt][ct], 0, 0, 0);
        __builtin_amdgcn_s_setprio(0);

        asm volatile("s_waitcnt lgkmcnt(0)" ::: "memory");   // bf1 ready
        __builtin_amdgcn_sched_barrier(0);

        __builtin_amdgcn_s_setprio(1);
#pragma unroll
        for (int rt = 0; rt < 2; ++rt)
#pragma unroll
            for (int ct = 0; ct < 2; ++ct)
                acc[rt][ct] = __builtin_amdgcn_mfma_i32_32x32x32_i8(
                    *(v4i*)&afbuf[par][1][rt], *(v4i*)&bf1[ct], acc[rt][ct], 0, 0, 0);
        __builtin_amdgcn_s_setprio(0);

        if (s < NSTEP - 1) {
            // retire own stage(s+1) share before barrier; leave af(s+1)
            // (+stage(s+2)) in flight. Our ds_reads already drained (lgkm 0).
            if (s <= 13)
                asm volatile("s_waitcnt vmcnt(5)" ::: "memory");
            else
                asm volatile("s_waitcnt vmcnt(4)" ::: "memory");
            __builtin_amdgcn_s_barrier();
        }
    }

    // ---- epilogue: packed argmin, exact tie-break (verified r6-r14) -------
    int sk[2];
#pragma unroll
    for (int ct = 0; ct < 2; ++ct) sk[ct] = sumk[n0 + ct * 32 + ln];

#pragma unroll
    for (int rt = 0; rt < 2; ++rt) {
#pragma unroll
        for (int r = 0; r < 16; ++r) {
            // verified C/D map: col = lane&31, row = (r&3)+8*(r>>2)+4*(lane>>5)
            const int qrow = m0 + wid * 64 + rt * 32 + (r & 3) + 8 * (r >> 2) + 4 * kh;
            uint32_t bmin = 0xFFFFFFFFu;
#pragma unroll
            for (int ct = 0; ct < 2; ++ct) {
                uint32_t dist = (uint32_t)(sk[ct] - 2 * acc[rt][ct][r] + 2048);
                uint32_t col  = (uint32_t)(n0 + ct * 32 + ln);
                bmin = min(bmin, (dist << 16) | col);
            }
#pragma unroll
            for (int off = 1; off < 32; off <<= 1)   // reduce within 32 cols
                bmin = min(bmin, (uint32_t)__shfl_xor((int)bmin, off, 64));
            if (ln == 0) atomicMin(&best[qrow], bmin);
        }
    }
}

// ---- best[q] -> gather values row ------------------------------------------
__global__ void finalize_kernel(const uint32_t* __restrict__ best,
                                const float* __restrict__ values,
                                float* __restrict__ out) {
    const int qy  = blockIdx.x;
    const int idx = (int)(best[qy] & 0xFFFFu);
    const float4* v4 = reinterpret_cast<const float4*>(values) + (size_t)idx * 256;
    float4* o4 = reinterpret_cast<float4*>(out) + (size_t)qy * 256;
    o4[threadIdx.x] = v4[threadIdx.x];
}

// ===========================================================================
// Fallback (round-5 VALU scan, 401 us) if ws_size can't hold i8 keys
// ===========================================================================
#define KCHUNK 256
#define NSPLIT (CAPACITY / KCHUNK)

__device__ __forceinline__ uint32_t pack_word(const int4* __restrict__ p) {
    uint32_t word = 0;
#pragma unroll
    for (int j = 0; j < 8; ++j) {
        int4 v = p[j];
        word |= (uint32_t)(v.x & 1) << (4 * j + 0);
        word |= (uint32_t)(v.y & 1) << (4 * j + 1);
        word |= (uint32_t)(v.z & 1) << (4 * j + 2);
        word |= (uint32_t)(v.w & 1) << (4 * j + 3);
    }
    return word;
}

__global__ void pack_bits_kernel(const int* __restrict__ in,
                                 uint32_t* __restrict__ out, int nwords) {
    int w = blockIdx.x * blockDim.x + threadIdx.x;
    if (w >= nwords) return;
    out[w] = pack_word(reinterpret_cast<const int4*>(in) + (size_t)w * 8);
}

__launch_bounds__(256, 4)
__global__ void scan_kernel(const uint32_t* __restrict__ qpack,
                            const uint32_t* __restrict__ kpack,
                            uint32_t* __restrict__ best) {
    const int t      = threadIdx.x;
    const int lane   = t & 63;
    const int wid    = t >> 6;
    const int ksplit = blockIdx.x & (NSPLIT - 1);
    const int qgb    = blockIdx.x >> 8;
    const int query  = qgb * 256 + wid * 64 + lane;

    uint32_t q[32];
    const uint4* qp4 = reinterpret_cast<const uint4*>(qpack + (size_t)query * 32);
#pragma unroll
    for (int j = 0; j < 8; ++j) {
        uint4 v = qp4[j];
        q[4 * j + 0] = v.x; q[4 * j + 1] = v.y;
        q[4 * j + 2] = v.z; q[4 * j + 3] = v.w;
    }
    uint32_t bst = 0xFFFFFFFFu;
    const int k0 = ksplit * KCHUNK;
#pragma unroll 2
    for (int k = k0; k < k0 + KCHUNK; ++k) {
        const uint4* kw4 = reinterpret_cast<const uint4*>(kpack + (size_t)k * 32);
        uint32_t dist = 0;
#pragma unroll
        for (int j = 0; j < 8; ++j) {
            uint4 kv = kw4[j];
            dist += __popc(kv.x ^ q[4 * j + 0]);
            dist += __popc(kv.y ^ q[4 * j + 1]);
            dist += __popc(kv.z ^ q[4 * j + 2]);
            dist += __popc(kv.w ^ q[4 * j + 3]);
        }
        bst = min(bst, (dist << 16) | (uint32_t)k);
    }
    atomicMin(&best[query], bst);
}

// ===========================================================================
extern "C" void kernel_launch(void* const* d_in, const int* in_sizes, int n_in,
                              void* d_out, int out_size, void* d_ws, size_t ws_size,
                              hipStream_t stream) {
    const int*   query  = (const int*)d_in[0];   // [2048, 1024] int32 0/1
    const int*   keys   = (const int*)d_in[1];   // [65536, 1024] int32 0/1
    const float* values = (const float*)d_in[2]; // [65536, 1024] f32
    float*       out    = (float*)d_out;         // [2048, 1024] f32
    char* ws = (char*)d_ws;

    const size_t need = 2097152ULL + 67108864ULL + 262144ULL + 8192ULL;
    if (ws_size >= need) {
        uint32_t* qT  = (uint32_t*)ws;                           // 2 MB blocked-T
        unsigned char* ki8 = (unsigned char*)(ws + 2097152);     // 64 MB
        int* sumk = (int*)(ws + 2097152 + 67108864);             // 256 KB
        uint32_t* best = (uint32_t*)(ws + 2097152 + 67108864 + 262144);

        init_best_kernel<<<BATCH / 256, 256, 0, stream>>>(best);
        prep_qT_kernel<<<BATCH,    256, 0, stream>>>(query, qT);
        prep_i8_kernel<<<CAPACITY, 256, 0, stream>>>(keys, ki8, sumk);
        gemm_scan_kernel<<<8192, 256, 0, stream>>>(
            reinterpret_cast<const uint4*>(qT), ki8, sumk, best);
        finalize_kernel<<<BATCH, 256, 0, stream>>>(best, values, out);
    } else {
        uint32_t* qpack = (uint32_t*)ws;                         // 256 KB
        uint32_t* kpack = (uint32_t*)(ws + 262144);              // 8 MB
        uint32_t* best  = (uint32_t*)(ws + 262144 + 8388608);    // 8 KB

        init_best_kernel<<<BATCH / 256, 256, 0, stream>>>(best);
        pack_bits_kernel<<<BATCH * 32 / 256, 256, 0, stream>>>(query, qpack, BATCH * 32);
        pack_bits_kernel<<<CAPACITY * 32 / 256, 256, 0, stream>>>(keys, kpack, CAPACITY * 32);
        scan_kernel<<<8 * NSPLIT, 256, 0, stream>>>(qpack, kpack, best);
        finalize_kernel<<<BATCH, 256, 0, stream>>>(best, values, out);
    }
}

// Round 16
// 473.814 us; speedup vs baseline: 1.2771x; 1.2771x over previous
//
#include <hip/hip_runtime.h>
#include <stdint.h>

typedef int v4i  __attribute__((ext_vector_type(4)));
typedef int v16i __attribute__((ext_vector_type(16)));

#define CAPACITY  65536
#define BATCH     2048
#define KBITS     1024
#define NUNIT     32      // K-units of 32 bytes; 32 x 32 = 1024 K
#define AS1 __attribute__((address_space(1)))
#define AS3 __attribute__((address_space(3)))

// ===========================================================================
// MFMA path: dist(q,k) = sumq + sumk - 2*dot(q,k); sumq dropped (constant per
// argmin row); rank by packed ((sumk - 2*dot + 2048)<<16) | key_idx -> exact
// first-max argmax (min dist, tie -> min index).
//
// m201-style 8-phase schedule ported to i8: 256x256 block tile, 8 waves
// (2Mx4N, wave tile 128x64, acc[4][2]), 32 phases (one 32-byte K-unit each):
//   stage(unit g+3) -> vmcnt(6) -> barrier -> 6x ds_read_b128 -> lgkmcnt(0)
//   -> setprio(1) + 8 MFMA + setprio(0) -> barrier
// K-plane-major LDS [slot][kplane][row][16B]: fragment reads lane-consecutive
// = bank-conflict-free, no swizzle; staging sources are K-plane-major global
// layouts so global_load_lds is linear in LDS AND coalesced in global.
// ===========================================================================

// ---- transposed pack: bits -> i8 in K-plane-major [kplane(64)][row][16B] ----
__global__ void prep_qT_kernel(const int* __restrict__ in,
                               uint32_t* __restrict__ outT) {
    const int row = blockIdx.x, t = threadIdx.x;   // t covers bits 4t..4t+3
    int4 v = reinterpret_cast<const int4*>(in)[(size_t)row * 256 + t];
    uint32_t b = (uint32_t)(v.x & 1)        | ((uint32_t)(v.y & 1) << 8) |
                 ((uint32_t)(v.z & 1) << 16) | ((uint32_t)(v.w & 1) << 24);
    outT[(size_t)(t >> 2) * (BATCH * 4) + (size_t)row * 4 + (t & 3)] = b;
}

__global__ void prep_kT_kernel(const int* __restrict__ in,
                               uint32_t* __restrict__ outT,
                               int* __restrict__ sums) {
    const int row = blockIdx.x, t = threadIdx.x;
    int4 v = reinterpret_cast<const int4*>(in)[(size_t)row * 256 + t];
    uint32_t b = (uint32_t)(v.x & 1)        | ((uint32_t)(v.y & 1) << 8) |
                 ((uint32_t)(v.z & 1) << 16) | ((uint32_t)(v.w & 1) << 24);
    outT[(size_t)(t >> 2) * (CAPACITY * 4) + (size_t)row * 4 + (t & 3)] = b;
    int s = (v.x & 1) + (v.y & 1) + (v.z & 1) + (v.w & 1);
    for (int off = 32; off; off >>= 1) s += __shfl_xor(s, off, 64);
    __shared__ int ws4[4];
    if ((t & 63) == 0) ws4[t >> 6] = s;
    __syncthreads();
    if (t == 0) sums[row] = ws4[0] + ws4[1] + ws4[2] + ws4[3];
}

__global__ void init_best_kernel(uint32_t* __restrict__ best) {
    best[blockIdx.x * 256 + threadIdx.x] = 0xFFFFFFFFu;
}

// ---- GEMM + fused argmin, 8-phase ------------------------------------------
__launch_bounds__(512, 2)
__global__ void gemm_scan_kernel(const uint4* __restrict__ aT4,  // [64][2048]
                                 const uint4* __restrict__ kT4,  // [64][65536]
                                 const int* __restrict__ sumk,
                                 uint32_t* __restrict__ best) {
    // 4 K-unit slots x (2 kplanes x 256 rows) x 16B, A and B: 64 KB total
    __shared__ uint4 sA[4][512];
    __shared__ uint4 sB[4][512];

    const int t    = threadIdx.x;                  // 512 = 8 waves
    const int lane = t & 63, wid = t >> 6;
    const int wr   = wid >> 2, wc = wid & 3;       // wave grid 2M x 4N
    const int ln   = lane & 31, kh = lane >> 5;    // mfma lane, K-half

    // XCD-pinned, mtile-inner (r7/r11 pattern: B-tile L2-hot, FETCH ~41MB):
    // xcd = b&7 owns ntiles [xcd*32, xcd*32+32); 8 consecutive blocks share
    // one B-tile (256 KB) across mtiles 0..7.
    const int b     = blockIdx.x;                  // [0, 2048)
    const int slot_ = b >> 3;                      // [0, 256)
    const int mtile = slot_ & 7;                   // [0, 8)   inner
    const int ntile = (b & 7) * 32 + (slot_ >> 3); // [0, 256)
    const int m0 = mtile * 256, n0 = ntile * 256;

    // staging decomposition: thread t covers (kplane = t>>8, row = t&255);
    // per wave: kplane uniform, row lane-consecutive -> LDS linear + global
    // coalesced (K-plane-major global layout).
    const int spl = t >> 8, srow = t & 255;
    const uint4* aSrc = aT4 + (size_t)spl * BATCH    + m0 + srow;
    const uint4* bSrc = kT4 + (size_t)spl * CAPACITY + n0 + srow;
    uint4* aDst = &sA[0][spl * 256 + srow];        // slot added via [g&3]
    uint4* bDst = &sB[0][spl * 256 + srow];

    auto STAGE_UNIT = [&](int g) {                 // 2 loads/thread (A+B)
        const int sl = g & 3;
        __builtin_amdgcn_global_load_lds(
            (const AS1 void*)(aSrc + (size_t)(g * 2) * BATCH),
            (AS3 void*)(aDst + sl * 512), 16, 0, 0);
        __builtin_amdgcn_global_load_lds(
            (const AS1 void*)(bSrc + (size_t)(g * 2) * CAPACITY),
            (AS3 void*)(bDst + sl * 512), 16, 0, 0);
    };

    // fragment LDS offsets (uint4 idx within a slot; K-invariant)
    int offA[4], offB[2];
#pragma unroll
    for (int rt = 0; rt < 4; ++rt) offA[rt] = kh * 256 + wr * 128 + rt * 32 + ln;
#pragma unroll
    for (int ct = 0; ct < 2; ++ct) offB[ct] = kh * 256 + wc * 64 + ct * 32 + ln;

    v16i acc[4][2];
#pragma unroll
    for (int rt = 0; rt < 4; ++rt)
#pragma unroll
        for (int ct = 0; ct < 2; ++ct)
#pragma unroll
            for (int e = 0; e < 16; ++e) acc[rt][ct][e] = 0;

    // prologue: prime units 0,1,2 (6 loads in flight)
    STAGE_UNIT(0);
    STAGE_UNIT(1);
    STAGE_UNIT(2);

#pragma unroll
    for (int g = 0; g < NUNIT; ++g) {
        const int sl = g & 3;

        if (g + 3 < NUNIT) STAGE_UNIT(g + 3);      // issue; stays in flight

        // retire unit g's 2 loads; units g+1..g+3 (2 each) stay in flight
        if (g <= NUNIT - 4)
            asm volatile("s_waitcnt vmcnt(6)" ::: "memory");
        else if (g == NUNIT - 3)
            asm volatile("s_waitcnt vmcnt(4)" ::: "memory");
        else if (g == NUNIT - 2)
            asm volatile("s_waitcnt vmcnt(2)" ::: "memory");
        else
            asm volatile("s_waitcnt vmcnt(0)" ::: "memory");
        __builtin_amdgcn_s_barrier();              // unit g visible to all

        uint4 af[4], bf[2];
#pragma unroll
        for (int rt = 0; rt < 4; ++rt) af[rt] = sA[sl][offA[rt]];
#pragma unroll
        for (int ct = 0; ct < 2; ++ct) bf[ct] = sB[sl][offB[ct]];

        asm volatile("s_waitcnt lgkmcnt(0)" ::: "memory");
        __builtin_amdgcn_sched_barrier(0);

        __builtin_amdgcn_s_setprio(1);
#pragma unroll
        for (int rt = 0; rt < 4; ++rt)
#pragma unroll
            for (int ct = 0; ct < 2; ++ct)
                acc[rt][ct] = __builtin_amdgcn_mfma_i32_32x32x32_i8(
                    *(v4i*)&af[rt], *(v4i*)&bf[ct], acc[rt][ct], 0, 0, 0);
        __builtin_amdgcn_s_setprio(0);

        // slot sl is re-staged (unit g+4) next phase: all reads must be done
        if (g + 1 < NUNIT) __builtin_amdgcn_s_barrier();
    }

    // ---- epilogue: packed argmin, exact tie-break (verified r6-r14) -------
    int sk[2];
#pragma unroll
    for (int ct = 0; ct < 2; ++ct) sk[ct] = sumk[n0 + wc * 64 + ct * 32 + ln];

#pragma unroll
    for (int rt = 0; rt < 4; ++rt) {
#pragma unroll
        for (int r = 0; r < 16; ++r) {
            // verified C/D map: col = lane&31, row = (r&3)+8*(r>>2)+4*(lane>>5)
            const int qrow = m0 + wr * 128 + rt * 32 + (r & 3) + 8 * (r >> 2) + 4 * kh;
            uint32_t bmin = 0xFFFFFFFFu;
#pragma unroll
            for (int ct = 0; ct < 2; ++ct) {
                uint32_t dist = (uint32_t)(sk[ct] - 2 * acc[rt][ct][r] + 2048);
                uint32_t col  = (uint32_t)(n0 + wc * 64 + ct * 32 + ln);
                bmin = min(bmin, (dist << 16) | col);
            }
#pragma unroll
            for (int off = 1; off < 32; off <<= 1)   // reduce within 32 cols
                bmin = min(bmin, (uint32_t)__shfl_xor((int)bmin, off, 64));
            if (ln == 0) atomicMin(&best[qrow], bmin);
        }
    }
}

// ---- best[q] -> gather values row ------------------------------------------
__global__ void finalize_kernel(const uint32_t* __restrict__ best,
                                const float* __restrict__ values,
                                float* __restrict__ out) {
    const int qy  = blockIdx.x;
    const int idx = (int)(best[qy] & 0xFFFFu);
    const float4* v4 = reinterpret_cast<const float4*>(values) + (size_t)idx * 256;
    float4* o4 = reinterpret_cast<float4*>(out) + (size_t)qy * 256;
    o4[threadIdx.x] = v4[threadIdx.x];
}

// ===========================================================================
// Fallback (round-5 VALU scan, 401 us) if ws_size can't hold transposed keys
// ===========================================================================
#define KCHUNK 256
#define NSPLIT (CAPACITY / KCHUNK)

__device__ __forceinline__ uint32_t pack_word(const int4* __restrict__ p) {
    uint32_t word = 0;
#pragma unroll
    for (int j = 0; j < 8; ++j) {
        int4 v = p[j];
        word |= (uint32_t)(v.x & 1) << (4 * j + 0);
        word |= (uint32_t)(v.y & 1) << (4 * j + 1);
        word |= (uint32_t)(v.z & 1) << (4 * j + 2);
        word |= (uint32_t)(v.w & 1) << (4 * j + 3);
    }
    return word;
}

__global__ void pack_bits_kernel(const int* __restrict__ in,
                                 uint32_t* __restrict__ out, int nwords) {
    int w = blockIdx.x * blockDim.x + threadIdx.x;
    if (w >= nwords) return;
    out[w] = pack_word(reinterpret_cast<const int4*>(in) + (size_t)w * 8);
}

__launch_bounds__(256, 4)
__global__ void scan_kernel(const uint32_t* __restrict__ qpack,
                            const uint32_t* __restrict__ kpack,
                            uint32_t* __restrict__ best) {
    const int t      = threadIdx.x;
    const int lane   = t & 63;
    const int wid    = t >> 6;
    const int ksplit = blockIdx.x & (NSPLIT - 1);
    const int qgb    = blockIdx.x >> 8;
    const int query  = qgb * 256 + wid * 64 + lane;

    uint32_t q[32];
    const uint4* qp4 = reinterpret_cast<const uint4*>(qpack + (size_t)query * 32);
#pragma unroll
    for (int j = 0; j < 8; ++j) {
        uint4 v = qp4[j];
        q[4 * j + 0] = v.x; q[4 * j + 1] = v.y;
        q[4 * j + 2] = v.z; q[4 * j + 3] = v.w;
    }
    uint32_t bst = 0xFFFFFFFFu;
    const int k0 = ksplit * KCHUNK;
#pragma unroll 2
    for (int k = k0; k < k0 + KCHUNK; ++k) {
        const uint4* kw4 = reinterpret_cast<const uint4*>(kpack + (size_t)k * 32);
        uint32_t dist = 0;
#pragma unroll
        for (int j = 0; j < 8; ++j) {
            uint4 kv = kw4[j];
            dist += __popc(kv.x ^ q[4 * j + 0]);
            dist += __popc(kv.y ^ q[4 * j + 1]);
            dist += __popc(kv.z ^ q[4 * j + 2]);
            dist += __popc(kv.w ^ q[4 * j + 3]);
        }
        bst = min(bst, (dist << 16) | (uint32_t)k);
    }
    atomicMin(&best[query], bst);
}

// ===========================================================================
extern "C" void kernel_launch(void* const* d_in, const int* in_sizes, int n_in,
                              void* d_out, int out_size, void* d_ws, size_t ws_size,
                              hipStream_t stream) {
    const int*   query  = (const int*)d_in[0];   // [2048, 1024] int32 0/1
    const int*   keys   = (const int*)d_in[1];   // [65536, 1024] int32 0/1
    const float* values = (const float*)d_in[2]; // [65536, 1024] f32
    float*       out    = (float*)d_out;         // [2048, 1024] f32
    char* ws = (char*)d_ws;

    const size_t need = 2097152ULL + 67108864ULL + 262144ULL + 8192ULL;
    if (ws_size >= need) {
        uint32_t* qT  = (uint32_t*)ws;                           // 2 MB  [64][2048][16B]
        uint32_t* kT  = (uint32_t*)(ws + 2097152);               // 64 MB [64][65536][16B]
        int* sumk = (int*)(ws + 2097152 + 67108864);             // 256 KB
        uint32_t* best = (uint32_t*)(ws + 2097152 + 67108864 + 262144);

        init_best_kernel<<<BATCH / 256, 256, 0, stream>>>(best);
        prep_qT_kernel<<<BATCH,    256, 0, stream>>>(query, qT);
        prep_kT_kernel<<<CAPACITY, 256, 0, stream>>>(keys, kT, sumk);
        gemm_scan_kernel<<<2048, 512, 0, stream>>>(
            reinterpret_cast<const uint4*>(qT),
            reinterpret_cast<const uint4*>(kT), sumk, best);
        finalize_kernel<<<BATCH, 256, 0, stream>>>(best, values, out);
    } else {
        uint32_t* qpack = (uint32_t*)ws;                         // 256 KB
        uint32_t* kpack = (uint32_t*)(ws + 262144);              // 8 MB
        uint32_t* best  = (uint32_t*)(ws + 262144 + 8388608);    // 8 KB

        init_best_kernel<<<BATCH / 256, 256, 0, stream>>>(best);
        pack_bits_kernel<<<BATCH * 32 / 256, 256, 0, stream>>>(query, qpack, BATCH * 32);
        pack_bits_kernel<<<CAPACITY * 32 / 256, 256, 0, stream>>>(keys, kpack, CAPACITY * 32);
        scan_kernel<<<8 * NSPLIT, 256, 0, stream>>>(qpack, kpack, best);
        finalize_kernel<<<BATCH, 256, 0, stream>>>(best, values, out);
    }
}

// Round 17
// 283.957 us; speedup vs baseline: 2.1310x; 1.6686x over previous
//
#include <hip/hip_runtime.h>
#include <stdint.h>

typedef int v4i  __attribute__((ext_vector_type(4)));
typedef int v16i __attribute__((ext_vector_type(16)));

#define CAPACITY  65536
#define BATCH     2048
#define KBITS     1024
#define NSTEP     16      // K-steps of 64 bytes

// ===========================================================================
// MFMA path: dist(q,k) = sumq + sumk - 2*dot(q,k). sumq constant per query
// row -> dropped; rank by packed ((sumk - 2*dot + 2048)<<16) | key_idx, exact
// (0 <= biased dist <= 3072 < 2^16), reproduces first-max argmax.
//
// Geometry: r14 verbatim (block 256M x 64N, 4 waves = 4 M-rows, wave 64x64,
// af double-buffered across the barrier, counted vmcnt, mtile-INNER XCD-
// pinned order). r17 adds EXACTLY ONE change: phase stagger. Co-resident
// blocks (bid, +256, +512, +768 under round-robin dispatch) sleep
// 0/1024/2048/3072 cyc (~1/4 of the measured 4200-cyc step) before the
// prologue, so their ds_read/L1/MFMA bursts interleave instead of landing
// simultaneously and serializing each pipe (r14's 25% MfmaUtil plateau).
// r15 tested stagger confounded with mtile-outer (which broke B locality);
// this isolates it.
// ===========================================================================

// ---- queries: bits -> i8, blocked-transposed qT[k/16][m][16] ----------------
__global__ void prep_qT_kernel(const int* __restrict__ in,
                               uint32_t* __restrict__ outT) {
    const int row = blockIdx.x, t = threadIdx.x;   // t covers bits 4t..4t+3
    int4 v = reinterpret_cast<const int4*>(in)[(size_t)row * 256 + t];
    uint32_t b = (uint32_t)(v.x & 1)        | ((uint32_t)(v.y & 1) << 8) |
                 ((uint32_t)(v.z & 1) << 16) | ((uint32_t)(v.w & 1) << 24);
    outT[(size_t)(t >> 2) * (BATCH * 4) + (size_t)row * 4 + (t & 3)] = b;
}

// ---- keys: bits -> i8 row-major, plus per-row bit count ---------------------
__global__ void prep_i8_kernel(const int* __restrict__ in,
                               unsigned char* __restrict__ out8,
                               int* __restrict__ sums) {
    const int row = blockIdx.x, t = threadIdx.x;
    int4 v = reinterpret_cast<const int4*>(in)[(size_t)row * 256 + t];
    uint32_t b = (uint32_t)(v.x & 1)        | ((uint32_t)(v.y & 1) << 8) |
                 ((uint32_t)(v.z & 1) << 16) | ((uint32_t)(v.w & 1) << 24);
    reinterpret_cast<uint32_t*>(out8)[(size_t)row * 256 + t] = b;
    int s = (v.x & 1) + (v.y & 1) + (v.z & 1) + (v.w & 1);
    for (int off = 32; off; off >>= 1) s += __shfl_xor(s, off, 64);
    __shared__ int ws4[4];
    if ((t & 63) == 0) ws4[t >> 6] = s;
    __syncthreads();
    if (t == 0) sums[row] = ws4[0] + ws4[1] + ws4[2] + ws4[3];
}

__global__ void init_best_kernel(uint32_t* __restrict__ best) {
    best[blockIdx.x * 256 + threadIdx.x] = 0xFFFFFFFFu;
}

// Involutive 16B-chunk swizzle within a [rows][64B] tile (idx = row*4+chunk):
// self-inverse, spreads consecutive rows across bank groups.
__device__ __forceinline__ int swz(int idx) { return idx ^ ((idx >> 3) & 7); }

// ---- GEMM + fused argmin ---------------------------------------------------
__launch_bounds__(256, 4)
__global__ void gemm_scan_kernel(const uint4* __restrict__ aT4,
                                 const unsigned char* __restrict__ ki8,
                                 const int* __restrict__ sumk,
                                 uint32_t* __restrict__ best) {
    __shared__ uint4 sB[3][256];   // 3 x (64 rows x 4 chunks) = 12 KB

    // ---- THE ONE CHANGE vs r14: phase stagger ----------------------------
    // Co-resident blocks differ in (bid>>8)&3; give each a distinct ~1/4-step
    // head start (s_sleep n ~= 64n cyc): 0 / 1024 / 2048 / 3072 cyc.
    {
        const int ph = (blockIdx.x >> 8) & 3;
        if (ph & 1) __builtin_amdgcn_s_sleep(16);   // +1024 cyc
        if (ph & 2) __builtin_amdgcn_s_sleep(32);   // +2048 cyc
    }

    const int t    = threadIdx.x;
    const int lane = t & 63, wid = t >> 6;        // wid = wave M-row
    const int ln   = lane & 31, kh = lane >> 5;   // mfma lane, k-half

    // mtile-inner, XCD-pinned: xcd = b&7 owns 128 ntiles; 8 consecutive
    // blocks share one B-tile (L2-hot); A (2 MB qT) cycles through L2.
    const int b     = blockIdx.x;
    const int slot  = b >> 3;                      // [0,1024)
    const int ntile = (b & 7) * 128 + (slot >> 3); // [0,1024)
    const int mtile = slot & 7;                    // [0,8)
    const int m0 = mtile * 256, n0 = ntile * 64;

    // B staging source, pre-swizzled (swz involution; LDS dest linear):
    const int sidx = swz(t);
    const unsigned char* bSrc =
        ki8 + (size_t)(n0 + (sidx >> 2)) * KBITS + (sidx & 3) * 16;
    auto STAGE_B = [&](int buf, int kc) {          // 1 x global_load_lds(16B)
        __builtin_amdgcn_global_load_lds(
            (const __attribute__((address_space(1))) void*)(bSrc + kc),
            (__attribute__((address_space(3))) void*)&sB[buf][wid * 64],
            16, 0, 0);
    };

    // B fragment LDS offsets (K-invariant), shared tile for all waves
    int offB[2][2];
#pragma unroll
    for (int km = 0; km < 2; ++km)
#pragma unroll
        for (int ct = 0; ct < 2; ++ct)
            offB[km][ct] = swz((ct * 32 + ln) * 4 + km * 2 + kh);

    const int mbase = m0 + wid * 64 + ln;          // unique per wave

    v16i acc[2][2];
#pragma unroll
    for (int rt = 0; rt < 2; ++rt)
#pragma unroll
        for (int ct = 0; ct < 2; ++ct)
#pragma unroll
            for (int e = 0; e < 16; ++e) acc[rt][ct][e] = 0;

    uint4 afbuf[2][2][2];                          // [parity][km][rt]
    auto LOAD_AF = [&](int par, int s) {
#pragma unroll
        for (int km = 0; km < 2; ++km)
#pragma unroll
            for (int rt = 0; rt < 2; ++rt)
                afbuf[par][km][rt] = aT4[(size_t)(s * 4 + km * 2 + kh) * BATCH
                                         + mbase + rt * 32];
    };

    // prologue: queue = stage(0)[1], stage(1)[1], af(0)[4].
    // vmcnt(5) retires stage(0); stage(1)+af(0) stay in flight.
    STAGE_B(0, 0);
    STAGE_B(1, 64);
    LOAD_AF(0, 0);
    asm volatile("s_waitcnt vmcnt(5)" ::: "memory");
    __builtin_amdgcn_s_barrier();

#pragma unroll
    for (int s = 0; s < NSTEP; ++s) {
        const int par = s & 1, buf = s % 3;

        if (s + 1 < NSTEP) LOAD_AF(par ^ 1, s + 1);       // 4 vm, 1-step slack
        if (s + 2 < NSTEP) STAGE_B((s + 2) % 3, (s + 2) * 64); // 1 vm, 2-step

        // B fragments: km=0 pair then km=1 pair (counted lgkm overlap)
        uint4 bf0[2], bf1[2];
#pragma unroll
        for (int ct = 0; ct < 2; ++ct) bf0[ct] = sB[buf][offB[0][ct]];
#pragma unroll
        for (int ct = 0; ct < 2; ++ct) bf1[ct] = sB[buf][offB[1][ct]];

        // retire af(s) (+ all older, incl. stage(s)); bf0 ready.
        // younger left in flight: stage(s+1), af(s+1), stage(s+2).
        if (s == 0)
            asm volatile("s_waitcnt vmcnt(5) lgkmcnt(2)" ::: "memory");
        else if (s <= 13)
            asm volatile("s_waitcnt vmcnt(6) lgkmcnt(2)" ::: "memory");
        else if (s == 14)
            asm volatile("s_waitcnt vmcnt(5) lgkmcnt(2)" ::: "memory");
        else
            asm volatile("s_waitcnt vmcnt(0) lgkmcnt(2)" ::: "memory");
        __builtin_amdgcn_sched_barrier(0);

        __builtin_amdgcn_s_setprio(1);
#pragma unroll
        for (int rt = 0; rt < 2; ++rt)
#pragma unroll
            for (int ct = 0; ct < 2; ++ct)
                acc[rt][ct] = __builtin_amdgcn_mfma_i32_32x32x32_i8(
                    *(v4i*)&afbuf[par][0][rt], *(v4i*)&bf0[ct], acc[rt][ct], 0, 0, 0);
        __builtin_amdgcn_s_setprio(0);

        asm volatile("s_waitcnt lgkmcnt(0)" ::: "memory");   // bf1 ready
        __builtin_amdgcn_sched_barrier(0);

        __builtin_amdgcn_s_setprio(1);
#pragma unroll
        for (int rt = 0; rt < 2; ++rt)
#pragma unroll
            for (int ct = 0; ct < 2; ++ct)
                acc[rt][ct] = __builtin_amdgcn_mfma_i32_32x32x32_i8(
                    *(v4i*)&afbuf[par][1][rt], *(v4i*)&bf1[ct], acc[rt][ct], 0, 0, 0);
        __builtin_amdgcn_s_setprio(0);

        if (s < NSTEP - 1) {
            // retire own stage(s+1) share before barrier; leave af(s+1)
            // (+stage(s+2)) in flight. Our ds_reads already drained (lgkm 0).
            if (s <= 13)
                asm volatile("s_waitcnt vmcnt(5)" ::: "memory");
            else
                asm volatile("s_waitcnt vmcnt(4)" ::: "memory");
            __builtin_amdgcn_s_barrier();
        }
    }

    // ---- epilogue: packed argmin, exact tie-break (verified r6-r14) -------
    int sk[2];
#pragma unroll
    for (int ct = 0; ct < 2; ++ct) sk[ct] = sumk[n0 + ct * 32 + ln];

#pragma unroll
    for (int rt = 0; rt < 2; ++rt) {
#pragma unroll
        for (int r = 0; r < 16; ++r) {
            // verified C/D map: col = lane&31, row = (r&3)+8*(r>>2)+4*(lane>>5)
            const int qrow = m0 + wid * 64 + rt * 32 + (r & 3) + 8 * (r >> 2) + 4 * kh;
            uint32_t bmin = 0xFFFFFFFFu;
#pragma unroll
            for (int ct = 0; ct < 2; ++ct) {
                uint32_t dist = (uint32_t)(sk[ct] - 2 * acc[rt][ct][r] + 2048);
                uint32_t col  = (uint32_t)(n0 + ct * 32 + ln);
                bmin = min(bmin, (dist << 16) | col);
            }
#pragma unroll
            for (int off = 1; off < 32; off <<= 1)   // reduce within 32 cols
                bmin = min(bmin, (uint32_t)__shfl_xor((int)bmin, off, 64));
            if (ln == 0) atomicMin(&best[qrow], bmin);
        }
    }
}

// ---- best[q] -> gather values row ------------------------------------------
__global__ void finalize_kernel(const uint32_t* __restrict__ best,
                                const float* __restrict__ values,
                                float* __restrict__ out) {
    const int qy  = blockIdx.x;
    const int idx = (int)(best[qy] & 0xFFFFu);
    const float4* v4 = reinterpret_cast<const float4*>(values) + (size_t)idx * 256;
    float4* o4 = reinterpret_cast<float4*>(out) + (size_t)qy * 256;
    o4[threadIdx.x] = v4[threadIdx.x];
}

// ===========================================================================
// Fallback (round-5 VALU scan, 401 us) if ws_size can't hold i8 keys
// ===========================================================================
#define KCHUNK 256
#define NSPLIT (CAPACITY / KCHUNK)

__device__ __forceinline__ uint32_t pack_word(const int4* __restrict__ p) {
    uint32_t word = 0;
#pragma unroll
    for (int j = 0; j < 8; ++j) {
        int4 v = p[j];
        word |= (uint32_t)(v.x & 1) << (4 * j + 0);
        word |= (uint32_t)(v.y & 1) << (4 * j + 1);
        word |= (uint32_t)(v.z & 1) << (4 * j + 2);
        word |= (uint32_t)(v.w & 1) << (4 * j + 3);
    }
    return word;
}

__global__ void pack_bits_kernel(const int* __restrict__ in,
                                 uint32_t* __restrict__ out, int nwords) {
    int w = blockIdx.x * blockDim.x + threadIdx.x;
    if (w >= nwords) return;
    out[w] = pack_word(reinterpret_cast<const int4*>(in) + (size_t)w * 8);
}

__launch_bounds__(256, 4)
__global__ void scan_kernel(const uint32_t* __restrict__ qpack,
                            const uint32_t* __restrict__ kpack,
                            uint32_t* __restrict__ best) {
    const int t      = threadIdx.x;
    const int lane   = t & 63;
    const int wid    = t >> 6;
    const int ksplit = blockIdx.x & (NSPLIT - 1);
    const int qgb    = blockIdx.x >> 8;
    const int query  = qgb * 256 + wid * 64 + lane;

    uint32_t q[32];
    const uint4* qp4 = reinterpret_cast<const uint4*>(qpack + (size_t)query * 32);
#pragma unroll
    for (int j = 0; j < 8; ++j) {
        uint4 v = qp4[j];
        q[4 * j + 0] = v.x; q[4 * j + 1] = v.y;
        q[4 * j + 2] = v.z; q[4 * j + 3] = v.w;
    }
    uint32_t bst = 0xFFFFFFFFu;
    const int k0 = ksplit * KCHUNK;
#pragma unroll 2
    for (int k = k0; k < k0 + KCHUNK; ++k) {
        const uint4* kw4 = reinterpret_cast<const uint4*>(kpack + (size_t)k * 32);
        uint32_t dist = 0;
#pragma unroll
        for (int j = 0; j < 8; ++j) {
            uint4 kv = kw4[j];
            dist += __popc(kv.x ^ q[4 * j + 0]);
            dist += __popc(kv.y ^ q[4 * j + 1]);
            dist += __popc(kv.z ^ q[4 * j + 2]);
            dist += __popc(kv.w ^ q[4 * j + 3]);
        }
        bst = min(bst, (dist << 16) | (uint32_t)k);
    }
    atomicMin(&best[query], bst);
}

// ===========================================================================
extern "C" void kernel_launch(void* const* d_in, const int* in_sizes, int n_in,
                              void* d_out, int out_size, void* d_ws, size_t ws_size,
                              hipStream_t stream) {
    const int*   query  = (const int*)d_in[0];   // [2048, 1024] int32 0/1
    const int*   keys   = (const int*)d_in[1];   // [65536, 1024] int32 0/1
    const float* values = (const float*)d_in[2]; // [65536, 1024] f32
    float*       out    = (float*)d_out;         // [2048, 1024] f32
    char* ws = (char*)d_ws;

    const size_t need = 2097152ULL + 67108864ULL + 262144ULL + 8192ULL;
    if (ws_size >= need) {
        uint32_t* qT  = (uint32_t*)ws;                           // 2 MB blocked-T
        unsigned char* ki8 = (unsigned char*)(ws + 2097152);     // 64 MB
        int* sumk = (int*)(ws + 2097152 + 67108864);             // 256 KB
        uint32_t* best = (uint32_t*)(ws + 2097152 + 67108864 + 262144);

        init_best_kernel<<<BATCH / 256, 256, 0, stream>>>(best);
        prep_qT_kernel<<<BATCH,    256, 0, stream>>>(query, qT);
        prep_i8_kernel<<<CAPACITY, 256, 0, stream>>>(keys, ki8, sumk);
        gemm_scan_kernel<<<8192, 256, 0, stream>>>(
            reinterpret_cast<const uint4*>(qT), ki8, sumk, best);
        finalize_kernel<<<BATCH, 256, 0, stream>>>(best, values, out);
    } else {
        uint32_t* qpack = (uint32_t*)ws;                         // 256 KB
        uint32_t* kpack = (uint32_t*)(ws + 262144);              // 8 MB
        uint32_t* best  = (uint32_t*)(ws + 262144 + 8388608);    // 8 KB

        init_best_kernel<<<BATCH / 256, 256, 0, stream>>>(best);
        pack_bits_kernel<<<BATCH * 32 / 256, 256, 0, stream>>>(query, qpack, BATCH * 32);
        pack_bits_kernel<<<CAPACITY * 32 / 256, 256, 0, stream>>>(keys, kpack, CAPACITY * 32);
        scan_kernel<<<8 * NSPLIT, 256, 0, stream>>>(qpack, kpack, best);
        finalize_kernel<<<BATCH, 256, 0, stream>>>(best, values, out);
    }
}